// Round 4
// baseline (767.448 us; speedup 1.0000x reference)
//
#include <hip/hip_runtime.h>
#include <hip/hip_bf16.h>

#define BQ 16      // batches
#define NG 64      // groups
#define SQ 4096    // sequence tokens
#define CD 768     // channels
#define ROWS (BQ*NG)
#define KS 12      // split-K factor (768/64)

// ---------------------------------------------------------------------------
// transpose64: dst[N x M] = src[M x N]^T, 64x64 LDS tiles, coalesced both ways
// ---------------------------------------------------------------------------
__global__ __launch_bounds__(256)
void transpose64(const float* __restrict__ src, float* __restrict__ dst,
                 int M, int N)
{
    __shared__ float t[64][65];
    const int bx = blockIdx.x * 64;   // col base in src
    const int by = blockIdx.y * 64;   // row base in src
    const int tx = threadIdx.x & 63, tw = threadIdx.x >> 6;
#pragma unroll
    for (int i = 0; i < 16; ++i) {
        const int row = i * 4 + tw;
        t[row][tx] = src[(size_t)(by + row) * N + bx + tx];
    }
    __syncthreads();
#pragma unroll
    for (int i = 0; i < 16; ++i) {
        const int row = i * 4 + tw;
        dst[(size_t)(bx + row) * M + by + tx] = t[tx][row];
    }
}

// ---------------------------------------------------------------------------
// vecmatT: out[j] = sum_c Mm[c][j] * v[c]   (Mm row-major 768x768)
// ---------------------------------------------------------------------------
__global__ __launch_bounds__(256)
void vecmatT(const float* __restrict__ Mm, const float* __restrict__ v,
             float* __restrict__ out)
{
    __shared__ float red[4][64];
    const int j0 = blockIdx.x * 64;
    const int jl = threadIdx.x & 63;
    const int cs = threadIdx.x >> 6;
    double a = 0.0;
    for (int c = cs; c < CD; c += 4)
        a += (double)Mm[(size_t)c * CD + j0 + jl] * (double)v[c];
    red[cs][jl] = (float)a;
    __syncthreads();
    if (cs == 0) out[j0 + jl] = red[0][jl] + red[1][jl] + red[2][jl] + red[3][jl];
}

// ---------------------------------------------------------------------------
// delta_q: delta[r] = query[r,:].uq + bq.bk  (fp64)
// ---------------------------------------------------------------------------
__global__ __launch_bounds__(256)
void delta_q(const float* __restrict__ query, const float* __restrict__ uq,
             const float* __restrict__ bq, const float* __restrict__ bk,
             double* __restrict__ delta)
{
    const int r    = blockIdx.x * 4 + (threadIdx.x >> 6);
    const int lane = threadIdx.x & 63;
    double a = 0.0, b = 0.0;
    for (int c = lane; c < CD; c += 64) {
        a += (double)query[(size_t)r * CD + c] * (double)uq[c];
        b += (double)bq[c] * (double)bk[c];
    }
    a += b;
    for (int off = 32; off; off >>= 1) a += __shfl_down(a, off, 64);
    if (lane == 0) delta[r] = a;
}

// ---------------------------------------------------------------------------
// gemm64sk: one wave per block, 64x64 tile, 8x8 per lane, K=64 per block
// (split-K over blockIdx.z). AT is the A-operand TRANSPOSED [768][lda]
// (so staging is a direct copy). B row-major [768][ldb]. Writes partials.
// ---------------------------------------------------------------------------
__global__ __launch_bounds__(64)
void gemm64sk(const float* __restrict__ AT, int lda,
              const float* __restrict__ B, int ldb,
              float* __restrict__ P, int M)
{
    __shared__ float As[64][68];
    __shared__ float Bs[64][68];
    const int lane = threadIdx.x;
    const int c0 = blockIdx.x * 64, r0 = blockIdx.y * 64, k0 = blockIdx.z * 64;
    const int q4 = lane & 15, qr = lane >> 4;
#pragma unroll
    for (int i = 0; i < 16; ++i) {
        const int kk = i * 4 + qr;
        *(float4*)&As[kk][4 * q4] = *(const float4*)(AT + (size_t)(k0 + kk) * lda + r0 + 4 * q4);
        *(float4*)&Bs[kk][4 * q4] = *(const float4*)(B  + (size_t)(k0 + kk) * ldb + c0 + 4 * q4);
    }
    __syncthreads();
    const int rg = lane & 7, cg = lane >> 3;
    float acc[8][8];
#pragma unroll
    for (int i = 0; i < 8; ++i)
#pragma unroll
        for (int j = 0; j < 8; ++j) acc[i][j] = 0.f;

#pragma unroll 2
    for (int dd = 0; dd < 64; ++dd) {
        const float4 a0 = *(const float4*)&As[dd][8 * rg];
        const float4 a1 = *(const float4*)&As[dd][8 * rg + 4];
        const float4 b0 = *(const float4*)&Bs[dd][8 * cg];
        const float4 b1 = *(const float4*)&Bs[dd][8 * cg + 4];
        const float av[8] = {a0.x, a0.y, a0.z, a0.w, a1.x, a1.y, a1.z, a1.w};
        const float bv[8] = {b0.x, b0.y, b0.z, b0.w, b1.x, b1.y, b1.z, b1.w};
#pragma unroll
        for (int i = 0; i < 8; ++i)
#pragma unroll
            for (int j = 0; j < 8; ++j) acc[i][j] += av[i] * bv[j];
    }
    float* Pz = P + (size_t)blockIdx.z * M * CD;
#pragma unroll
    for (int i = 0; i < 8; ++i) {
        const int r = r0 + 8 * rg + i;
        float4 v0; v0.x = acc[i][0]; v0.y = acc[i][1]; v0.z = acc[i][2]; v0.w = acc[i][3];
        float4 v1; v1.x = acc[i][4]; v1.y = acc[i][5]; v1.z = acc[i][6]; v1.w = acc[i][7];
        *(float4*)(Pz + (size_t)r * CD + c0 + 8 * cg)     = v0;
        *(float4*)(Pz + (size_t)r * CD + c0 + 8 * cg + 4) = v1;
    }
}

// ---------------------------------------------------------------------------
// reduce_sk: out[e] = fp64 sum of KS partials (+ epilogue).
// mode 0: none; 1: +bias[c]; 3: invf*acc + bsc*bias2[c] + bias[c]
// ---------------------------------------------------------------------------
__global__ __launch_bounds__(256)
void reduce_sk(const float* __restrict__ P, const float* __restrict__ bias,
               const float* __restrict__ bias2, const int* __restrict__ cnt,
               float* __restrict__ out, int M, int mode)
{
    const int e = blockIdx.x * 256 + threadIdx.x;
    if (e >= M * CD) return;
    const size_t MN = (size_t)M * CD;
    double a = 0.0;
#pragma unroll
    for (int z = 0; z < KS; ++z) a += (double)P[z * MN + e];
    float v = (float)a;
    if (mode == 1) v += bias[e % CD];
    else if (mode == 3) {
        const int r = e / CD;
        const int cv = cnt[r];
        const float invf = 1.f / ((float)cv + 1.f);   // ASSIGN_EPS = 1
        v = v * invf + ((float)cv * invf) * bias2[e % CD] + bias[e % CD];
    }
    out[e] = v;
}

// ---------------------------------------------------------------------------
// score_argmax (UNCHANGED from round 3)
// ---------------------------------------------------------------------------
struct ScoreTiles { float gt[64][68]; float kt[64][132]; };
struct ScoreRed   { double bval[128][17]; int bidx[128][17]; };
union  ScoreShared { ScoreTiles t; ScoreRed r; };

__global__ __launch_bounds__(256)
void score_argmax(const float* __restrict__ g, const float* __restrict__ key,
                  const double* __restrict__ delta, int* __restrict__ idxo)
{
    __shared__ alignas(16) ScoreShared sh;
    __shared__ double dl[64];
    const int tid  = threadIdx.x;
    const int b    = blockIdx.y;
    const int s0   = blockIdx.x * 128;
    const int sg   = tid & 15;
    const int ng   = tid >> 4;
    const int lrow = tid >> 4;
    const int c4   = tid & 15;

    if (tid < 64) dl[tid] = delta[b * 64 + tid];

    float  accC[4][8];
    double acc64[4][8];
#pragma unroll
    for (int i = 0; i < 4; ++i)
#pragma unroll
        for (int j = 0; j < 8; ++j) { accC[i][j] = 0.f; acc64[i][j] = 0.0; }

    for (int kc = 0; kc < CD; kc += 64) {
#pragma unroll
        for (int p = 0; p < 4; ++p) {
            const int nrow = p * 16 + lrow;
            const float4 v = *(const float4*)(g + (size_t)(b * 64 + nrow) * CD + kc + 4 * c4);
            sh.t.gt[4*c4+0][nrow] = v.x; sh.t.gt[4*c4+1][nrow] = v.y;
            sh.t.gt[4*c4+2][nrow] = v.z; sh.t.gt[4*c4+3][nrow] = v.w;
        }
#pragma unroll
        for (int p = 0; p < 8; ++p) {
            const int srow = p * 16 + lrow;
            const float4 v = *(const float4*)(key + (size_t)(b * SQ + s0 + srow) * CD + kc + 4 * c4);
            sh.t.kt[4*c4+0][srow] = v.x; sh.t.kt[4*c4+1][srow] = v.y;
            sh.t.kt[4*c4+2][srow] = v.z; sh.t.kt[4*c4+3][srow] = v.w;
        }
        __syncthreads();
#pragma unroll 4
        for (int dd = 0; dd < 64; ++dd) {
            const float4 ga = *(const float4*)&sh.t.gt[dd][4 * ng];
            const float4 k0 = *(const float4*)&sh.t.kt[dd][8 * sg];
            const float4 k1 = *(const float4*)&sh.t.kt[dd][8 * sg + 4];
            const float gs[4] = { ga.x, ga.y, ga.z, ga.w };
            const float ks[8] = { k0.x, k0.y, k0.z, k0.w, k1.x, k1.y, k1.z, k1.w };
#pragma unroll
            for (int i = 0; i < 4; ++i)
#pragma unroll
                for (int j = 0; j < 8; ++j) accC[i][j] += gs[i] * ks[j];
        }
        __syncthreads();
#pragma unroll
        for (int i = 0; i < 4; ++i)
#pragma unroll
            for (int j = 0; j < 8; ++j) { acc64[i][j] += (double)accC[i][j]; accC[i][j] = 0.f; }
    }

    double bv[8]; int bn[8];
#pragma unroll
    for (int j = 0; j < 8; ++j) {
        bv[j] = acc64[0][j] + dl[4 * ng + 0]; bn[j] = 4 * ng + 0;
#pragma unroll
        for (int i = 1; i < 4; ++i) {
            const double v = acc64[i][j] + dl[4 * ng + i];
            if (v > bv[j]) { bv[j] = v; bn[j] = 4 * ng + i; }
        }
    }
    __syncthreads();
#pragma unroll
    for (int j = 0; j < 8; ++j) {
        sh.r.bval[8 * sg + j][ng] = bv[j];
        sh.r.bidx[8 * sg + j][ng] = bn[j];
    }
    __syncthreads();
    if (tid < 128) {
        const int s = tid;
        double best = sh.r.bval[s][0]; int bi = sh.r.bidx[s][0];
        for (int k = 1; k < 16; ++k) {
            const double v = sh.r.bval[s][k];
            if (v > best) { best = v; bi = sh.r.bidx[s][k]; }
        }
        idxo[b * SQ + s0 + s] = bi;
    }
}

// ---------------------------------------------------------------------------
// gather_ksum (UNCHANGED from round 3)
// ---------------------------------------------------------------------------
__global__ __launch_bounds__(256)
void gather_ksum(const float* __restrict__ key, const int* __restrict__ idx,
                 float* __restrict__ Ksum, int* __restrict__ cnt)
{
    __shared__ int slist[SQ];
    __shared__ int scount;
    const int n   = blockIdx.x;
    const int b   = blockIdx.y;
    const int tid = threadIdx.x;
    if (tid == 0) scount = 0;
    __syncthreads();

    const int* ib = idx + b * SQ;
#pragma unroll
    for (int p = 0; p < SQ / 256; ++p) {
        const int s = p * 256 + tid;
        if (ib[s] == n) {
            const int pos = atomicAdd(&scount, 1);
            slist[pos] = s;
        }
    }
    __syncthreads();
    const int m = scount;

    double a0 = 0.0, a1 = 0.0, a2 = 0.0;
    const float* kb = key + (size_t)b * SQ * CD;
    const int c1 = tid + 256, c2 = tid + 512;

    int r = 0;
    for (; r + 4 <= m; r += 4) {
        const int s0 = slist[r], s1 = slist[r + 1], s2 = slist[r + 2], s3 = slist[r + 3];
        const float* p0 = kb + (size_t)s0 * CD;
        const float* p1 = kb + (size_t)s1 * CD;
        const float* p2 = kb + (size_t)s2 * CD;
        const float* p3 = kb + (size_t)s3 * CD;
        a0 += (double)p0[tid] + (double)p1[tid] + (double)p2[tid] + (double)p3[tid];
        a1 += (double)p0[c1] + (double)p1[c1] + (double)p2[c1] + (double)p3[c1];
        a2 += (double)p0[c2] + (double)p1[c2] + (double)p2[c2] + (double)p3[c2];
    }
    for (; r < m; ++r) {
        const float* p0 = kb + (size_t)slist[r] * CD;
        a0 += (double)p0[tid]; a1 += (double)p0[c1]; a2 += (double)p0[c2];
    }

    float* out = Ksum + (size_t)(b * 64 + n) * CD;
    out[tid] = (float)a0; out[c1] = (float)a1; out[c2] = (float)a2;
    if (tid == 0) cnt[b * 64 + n] = m;
}

// ---------------------------------------------------------------------------
extern "C" void kernel_launch(void* const* d_in, const int* in_sizes, int n_in,
                              void* d_out, int out_size, void* d_ws, size_t ws_size,
                              hipStream_t stream)
{
    const float* query = (const float*)d_in[0];
    const float* key   = (const float*)d_in[1];
    const float* Wq    = (const float*)d_in[2];
    const float* bq    = (const float*)d_in[3];
    const float* Wk    = (const float*)d_in[4];
    const float* bk    = (const float*)d_in[5];
    const float* Wv    = (const float*)d_in[6];
    const float* bv    = (const float*)d_in[7];
    const float* Wo    = (const float*)d_in[8];
    const float* bo    = (const float*)d_in[9];

    char* ws = (char*)d_ws;
    const size_t MB = 1 << 20;
    int*    cnt   = (int*)   (ws + 0);          //   4 KB
    double* delta = (double*)(ws + 4096);       //   8 KB
    float*  uq    = (float*) (ws + 16384);      //   3 KB
    float*  bqk   = (float*) (ws + 19456);      //   3 KB
    float*  bvo   = (float*) (ws + 22528);      //   3 KB
    int*    idx   = (int*)   (ws + 32768);      // 256 KB
    float*  qT    = (float*) (ws + 1 * MB);     //   3 MB  [768][1024]
    float*  WoT   = (float*) (ws + 4 * MB);     // 2.25 MB [768][768]
    float*  Wqk   = (float*) (ws + 7 * MB);     // 2.25 MB [768][768]
    float*  g     = (float*) (ws + 10 * MB);    //   3 MB  [1024][768]
    float*  Wvo   = (float*) (ws + 13 * MB);    // 2.25 MB [768][768]
    float*  Ksum  = (float*) (ws + 16 * MB);    //   3 MB
    float*  KsumT = (float*) (ws + 20 * MB);    //   3 MB  [768][1024]
    float*  P     = (float*) (ws + 24 * MB);    // 36 MB   partials

    // --- weight-only precomputes ---
    transpose64<<<dim3(12, 12), 256, 0, stream>>>(Wo, WoT, CD, CD);    // WoT = Wo^T
    vecmatT<<<12, 256, 0, stream>>>(Wq, bk, uq);                       // uq = Wq^T bk
    vecmatT<<<12, 256, 0, stream>>>(Wk, bq, bqk);                      // bqk = bq @ Wk
    vecmatT<<<12, 256, 0, stream>>>(WoT, bv, bvo);                     // bvo = bv @ Wo^T
    // Wqk = Wq^T @ Wk
    gemm64sk<<<dim3(12, 12, KS), 64, 0, stream>>>(Wq, CD, Wk, CD, P, CD);
    reduce_sk<<<2304, 256, 0, stream>>>(P, nullptr, nullptr, nullptr, Wqk, CD, 0);
    // Wvo = Wv^T @ Wo^T
    gemm64sk<<<dim3(12, 12, KS), 64, 0, stream>>>(Wv, CD, WoT, CD, P, CD);
    reduce_sk<<<2304, 256, 0, stream>>>(P, nullptr, nullptr, nullptr, Wvo, CD, 0);

    // --- data path ---
    transpose64<<<dim3(12, 16), 256, 0, stream>>>(query, qT, ROWS, CD);
    delta_q<<<ROWS / 4, 256, 0, stream>>>(query, uq, bq, bk, delta);
    // g = query @ Wqk + bqk
    gemm64sk<<<dim3(12, 16, KS), 64, 0, stream>>>(qT, ROWS, Wqk, CD, P, ROWS);
    reduce_sk<<<3072, 256, 0, stream>>>(P, bqk, nullptr, nullptr, g, ROWS, 1);
    // argmax assignment
    score_argmax<<<dim3(SQ / 128, BQ), 256, 0, stream>>>(g, key, delta, idx);
    // Ksum / cnt
    gather_ksum<<<dim3(NG, BQ), 256, 0, stream>>>(key, idx, Ksum, cnt);
    transpose64<<<dim3(12, 16), 256, 0, stream>>>(Ksum, KsumT, ROWS, CD);
    // out = invf*(Ksum @ Wvo) + bsc*bvo + bo
    gemm64sk<<<dim3(12, 16, KS), 64, 0, stream>>>(KsumT, ROWS, Wvo, CD, P, ROWS);
    reduce_sk<<<3072, 256, 0, stream>>>(P, bo, bvo, cnt, (float*)d_out, ROWS, 3);
}

// Round 5
// 579.921 us; speedup vs baseline: 1.3234x; 1.3234x over previous
//
#include <hip/hip_runtime.h>
#include <hip/hip_bf16.h>

#define BQ 16      // batches
#define NG 64      // groups
#define SQ 4096    // sequence tokens
#define CD 768     // channels
#define ROWS (BQ*NG)
#define KSP 4      // split-K factor (768 = 4 * 192)

// ---------------------------------------------------------------------------
// transpose64: dst[N x M] = src[M x N]^T, 64x64 LDS tiles
// ---------------------------------------------------------------------------
__global__ __launch_bounds__(256)
void transpose64(const float* __restrict__ src, float* __restrict__ dst,
                 int M, int N)
{
    __shared__ float t[64][65];
    const int bx = blockIdx.x * 64;
    const int by = blockIdx.y * 64;
    const int tx = threadIdx.x & 63, tw = threadIdx.x >> 6;
#pragma unroll
    for (int i = 0; i < 16; ++i) {
        const int row = i * 4 + tw;
        t[row][tx] = src[(size_t)(by + row) * N + bx + tx];
    }
    __syncthreads();
#pragma unroll
    for (int i = 0; i < 16; ++i) {
        const int row = i * 4 + tw;
        dst[(size_t)(bx + row) * M + by + tx] = t[tx][row];
    }
}

// ---------------------------------------------------------------------------
// vecmat3: three fused vec@mat precomputes (blockIdx.y selects)
//   y=0: uq  = Wq^T bk      y=1: bqk = bq @ Wk      y=2: bvo = bv @ Wo^T
// ---------------------------------------------------------------------------
__global__ __launch_bounds__(256)
void vecmat3(const float* __restrict__ Wq, const float* __restrict__ bk,
             const float* __restrict__ Wk, const float* __restrict__ bq,
             const float* __restrict__ WoT, const float* __restrict__ bv,
             float* __restrict__ uq, float* __restrict__ bqk,
             float* __restrict__ bvo)
{
    __shared__ float red[4][64];
    const float* Mm; const float* v; float* out;
    if (blockIdx.y == 0)      { Mm = Wq;  v = bk; out = uq;  }
    else if (blockIdx.y == 1) { Mm = Wk;  v = bq; out = bqk; }
    else                      { Mm = WoT; v = bv; out = bvo; }
    const int j0 = blockIdx.x * 64;
    const int jl = threadIdx.x & 63;
    const int cs = threadIdx.x >> 6;
    double a = 0.0;
    for (int c = cs; c < CD; c += 4)
        a += (double)Mm[(size_t)c * CD + j0 + jl] * (double)v[c];
    red[cs][jl] = (float)a;
    __syncthreads();
    if (cs == 0) out[j0 + jl] = red[0][jl] + red[1][jl] + red[2][jl] + red[3][jl];
}

// ---------------------------------------------------------------------------
// delta_q: delta[r] = query[r,:].uq + bq.bk  (fp64)
// ---------------------------------------------------------------------------
__global__ __launch_bounds__(256)
void delta_q(const float* __restrict__ query, const float* __restrict__ uq,
             const float* __restrict__ bq, const float* __restrict__ bk,
             double* __restrict__ delta)
{
    const int r    = blockIdx.x * 4 + (threadIdx.x >> 6);
    const int lane = threadIdx.x & 63;
    double a = 0.0, b = 0.0;
    for (int c = lane; c < CD; c += 64) {
        a += (double)query[(size_t)r * CD + c] * (double)uq[c];
        b += (double)bq[c] * (double)bk[c];
    }
    a += b;
    for (int off = 32; off; off >>= 1) a += __shfl_down(a, off, 64);
    if (lane == 0) delta[r] = a;
}

// ---------------------------------------------------------------------------
// gemm_core: 256-thread 64x64 tile, K=192 per call (3 chunks of 64),
// 4x4 per lane. AT is A TRANSPOSED [768][lda] (staging = direct copy).
// LDS pad 72 -> all fragment reads and staging stores <=2-way (free).
// fp32 per-64-chunk partials folded into fp64 (proven score-path recipe).
// Writes fp32 partial tile into Pz (row stride CD).
// ---------------------------------------------------------------------------
__device__ __forceinline__
void gemm_core(const float* __restrict__ AT, int lda,
               const float* __restrict__ B,  int ldb,
               float* __restrict__ Pz, int r0, int c0, int k0, int prow0)
{
    __shared__ float As[64][72];
    __shared__ float Bs[64][72];
    const int tid = threadIdx.x;
    const int c4  = tid & 15;     // staging float4 col
    const int kr  = tid >> 4;     // staging row step
    const int cg  = tid & 15;     // output col group
    const int rg  = tid >> 4;     // output row group

    float  acc[4][4]; double acc64[4][4];
#pragma unroll
    for (int i = 0; i < 4; ++i)
#pragma unroll
        for (int j = 0; j < 4; ++j) { acc[i][j] = 0.f; acc64[i][j] = 0.0; }

    for (int ch = 0; ch < 3; ++ch) {
        const int kb = k0 + ch * 64;
        if (ch) __syncthreads();
#pragma unroll
        for (int i = 0; i < 4; ++i) {
            const int row = i * 16 + kr;
            *(float4*)&As[row][4 * c4] = *(const float4*)(AT + (size_t)(kb + row) * lda + r0 + 4 * c4);
            *(float4*)&Bs[row][4 * c4] = *(const float4*)(B  + (size_t)(kb + row) * ldb + c0 + 4 * c4);
        }
        __syncthreads();
#pragma unroll 8
        for (int dd = 0; dd < 64; ++dd) {
            const float4 a = *(const float4*)&As[dd][4 * rg];
            const float4 b = *(const float4*)&Bs[dd][4 * cg];
            const float av[4] = {a.x, a.y, a.z, a.w};
            const float bv[4] = {b.x, b.y, b.z, b.w};
#pragma unroll
            for (int i = 0; i < 4; ++i)
#pragma unroll
                for (int j = 0; j < 4; ++j) acc[i][j] += av[i] * bv[j];
        }
#pragma unroll
        for (int i = 0; i < 4; ++i)
#pragma unroll
            for (int j = 0; j < 4; ++j) { acc64[i][j] += (double)acc[i][j]; acc[i][j] = 0.f; }
    }
#pragma unroll
    for (int i = 0; i < 4; ++i) {
        const int row = prow0 + 4 * rg + i;
        float4 v;
        v.x = (float)acc64[i][0]; v.y = (float)acc64[i][1];
        v.z = (float)acc64[i][2]; v.w = (float)acc64[i][3];
        *(float4*)(Pz + (size_t)row * CD + c0 + 4 * cg) = v;
    }
}

// weight GEMMs fused: by<12 -> Wqk = Wq^T@Wk; by>=12 -> Wvo = Wv^T@Wo^T
__global__ __launch_bounds__(256)
void gemm_w(const float* __restrict__ Wq, const float* __restrict__ Wk,
            const float* __restrict__ Wv, const float* __restrict__ WoT,
            float* __restrict__ P)
{
    const int by = blockIdx.y;
    float* Pz = P + (size_t)blockIdx.z * (1536 * CD);
    const float* AT; const float* Bp; int r0;
    if (by < 12) { AT = Wq; Bp = Wk;  r0 = by * 64; }
    else         { AT = Wv; Bp = WoT; r0 = (by - 12) * 64; }
    gemm_core(AT, CD, Bp, CD, Pz, r0, blockIdx.x * 64, blockIdx.z * 192, by * 64);
}

// data GEMM: out-rows M=1024, AT [768][1024]
__global__ __launch_bounds__(256)
void gemm_d(const float* __restrict__ AT, const float* __restrict__ B,
            float* __restrict__ P)
{
    float* Pz = P + (size_t)blockIdx.z * (ROWS * CD);
    const int r0 = blockIdx.y * 64;
    gemm_core(AT, ROWS, B, CD, Pz, r0, blockIdx.x * 64, blockIdx.z * 192, r0);
}

// ---------------------------------------------------------------------------
// reduce_sk: out[e] = fp64 sum of KSP partials (+ epilogue).
// mode 0: none; 1: +bias[c]; 3: invf*acc + bsc*bias2[c] + bias[c]
// ---------------------------------------------------------------------------
__global__ __launch_bounds__(256)
void reduce_sk(const float* __restrict__ P, const float* __restrict__ bias,
               const float* __restrict__ bias2, const int* __restrict__ cnt,
               float* __restrict__ out, int M, int mode)
{
    const int e = blockIdx.x * 256 + threadIdx.x;
    if (e >= M * CD) return;
    const size_t MN = (size_t)M * CD;
    double a = 0.0;
#pragma unroll
    for (int z = 0; z < KSP; ++z) a += (double)P[z * MN + e];
    float v = (float)a;
    if (mode == 1) v += bias[e % CD];
    else if (mode == 3) {
        const int r = e / CD;
        const int cv = cnt[r];
        const float invf = 1.f / ((float)cv + 1.f);   // ASSIGN_EPS = 1
        v = v * invf + ((float)cv * invf) * bias2[e % CD] + bias[e % CD];
    }
    out[e] = v;
}

// ---------------------------------------------------------------------------
// score_argmax: S[n][s] = g[b,n,:].key[b,s,:] + delta[n]; fp64 argmax over n.
// LDS fix vs R3: kt split into ktA/ktB (float4 halves) + per-dd rotation
// -> fragment reads 2-way (free) instead of 4-way. Accumulation order
// bit-identical to the proven R3 kernel.
// ---------------------------------------------------------------------------
struct ScoreTiles { float gt[64][68]; float ktA[64][64]; float ktB[64][64]; };
struct ScoreRed   { double bval[128][17]; int bidx[128][17]; };
union  ScoreShared { ScoreTiles t; ScoreRed r; };

__global__ __launch_bounds__(256)
void score_argmax(const float* __restrict__ g, const float* __restrict__ key,
                  const double* __restrict__ delta, int* __restrict__ idxo)
{
    __shared__ alignas(16) ScoreShared sh;
    __shared__ double dl[64];
    const int tid  = threadIdx.x;
    const int b    = blockIdx.y;
    const int s0   = blockIdx.x * 128;
    const int sg   = tid & 15;    // s = 8*sg + j
    const int ng   = tid >> 4;    // n = 4*ng + i
    const int lrow = tid >> 4;
    const int c4   = tid & 15;

    if (tid < 64) dl[tid] = delta[b * 64 + tid];

    float  accC[4][8];
    double acc64[4][8];
#pragma unroll
    for (int i = 0; i < 4; ++i)
#pragma unroll
        for (int j = 0; j < 8; ++j) { accC[i][j] = 0.f; acc64[i][j] = 0.0; }

    for (int kc = 0; kc < CD; kc += 64) {
        // stage g transposed: gt[k-local][n]
#pragma unroll
        for (int p = 0; p < 4; ++p) {
            const int nrow = p * 16 + lrow;
            const float4 v = *(const float4*)(g + (size_t)(b * 64 + nrow) * CD + kc + 4 * c4);
            sh.t.gt[4*c4+0][nrow] = v.x; sh.t.gt[4*c4+1][nrow] = v.y;
            sh.t.gt[4*c4+2][nrow] = v.z; sh.t.gt[4*c4+3][nrow] = v.w;
        }
        // stage key transposed, split + dd-rotated:
        //   s-group gs = s>>3, j = s&7; col = ((gs+dd)&15)*4 + (s&3)
        //   j<4 -> ktA, j>=4 -> ktB
#pragma unroll
        for (int p = 0; p < 8; ++p) {
            const int srow = p * 16 + lrow;
            const float4 v = *(const float4*)(key + (size_t)(b * SQ + s0 + srow) * CD + kc + 4 * c4);
            const int gs = srow >> 3;
            const int lo = srow & 3;
            const bool hi = (srow & 4) != 0;
            const float vv[4] = { v.x, v.y, v.z, v.w };
#pragma unroll
            for (int i = 0; i < 4; ++i) {
                const int dd = 4 * c4 + i;
                const int col = (((gs + dd) & 15) << 2) + lo;
                if (hi) sh.t.ktB[dd][col] = vv[i];
                else    sh.t.ktA[dd][col] = vv[i];
            }
        }
        __syncthreads();
#pragma unroll 4
        for (int dd = 0; dd < 64; ++dd) {
            const int cA = ((sg + dd) & 15) << 2;
            const float4 ga = *(const float4*)&sh.t.gt[dd][4 * ng];
            const float4 k0 = *(const float4*)&sh.t.ktA[dd][cA];
            const float4 k1 = *(const float4*)&sh.t.ktB[dd][cA];
            const float gs_[4] = { ga.x, ga.y, ga.z, ga.w };
            const float ks[8] = { k0.x, k0.y, k0.z, k0.w, k1.x, k1.y, k1.z, k1.w };
#pragma unroll
            for (int i = 0; i < 4; ++i)
#pragma unroll
                for (int j = 0; j < 8; ++j) accC[i][j] += gs_[i] * ks[j];
        }
        __syncthreads();
#pragma unroll
        for (int i = 0; i < 4; ++i)
#pragma unroll
            for (int j = 0; j < 8; ++j) { acc64[i][j] += (double)accC[i][j]; accC[i][j] = 0.f; }
    }

    double bv[8]; int bn[8];
#pragma unroll
    for (int j = 0; j < 8; ++j) {
        bv[j] = acc64[0][j] + dl[4 * ng + 0]; bn[j] = 4 * ng + 0;
#pragma unroll
        for (int i = 1; i < 4; ++i) {
            const double v = acc64[i][j] + dl[4 * ng + i];
            if (v > bv[j]) { bv[j] = v; bn[j] = 4 * ng + i; }
        }
    }
    __syncthreads();
#pragma unroll
    for (int j = 0; j < 8; ++j) {
        sh.r.bval[8 * sg + j][ng] = bv[j];
        sh.r.bidx[8 * sg + j][ng] = bn[j];
    }
    __syncthreads();
    if (tid < 128) {
        const int s = tid;
        double best = sh.r.bval[s][0]; int bi = sh.r.bidx[s][0];
        for (int k = 1; k < 16; ++k) {
            const double v = sh.r.bval[s][k];
            if (v > best) { best = v; bi = sh.r.bidx[s][k]; }
        }
        idxo[b * SQ + s0 + s] = bi;
    }
}

// ---------------------------------------------------------------------------
// gather_ksum (proven R3 kernel)
// ---------------------------------------------------------------------------
__global__ __launch_bounds__(256)
void gather_ksum(const float* __restrict__ key, const int* __restrict__ idx,
                 float* __restrict__ Ksum, int* __restrict__ cnt)
{
    __shared__ int slist[SQ];
    __shared__ int scount;
    const int n   = blockIdx.x;
    const int b   = blockIdx.y;
    const int tid = threadIdx.x;
    if (tid == 0) scount = 0;
    __syncthreads();

    const int* ib = idx + b * SQ;
#pragma unroll
    for (int p = 0; p < SQ / 256; ++p) {
        const int s = p * 256 + tid;
        if (ib[s] == n) {
            const int pos = atomicAdd(&scount, 1);
            slist[pos] = s;
        }
    }
    __syncthreads();
    const int m = scount;

    double a0 = 0.0, a1 = 0.0, a2 = 0.0;
    const float* kb = key + (size_t)b * SQ * CD;
    const int c1 = tid + 256, c2 = tid + 512;

    int r = 0;
    for (; r + 4 <= m; r += 4) {
        const float* p0 = kb + (size_t)slist[r]     * CD;
        const float* p1 = kb + (size_t)slist[r + 1] * CD;
        const float* p2 = kb + (size_t)slist[r + 2] * CD;
        const float* p3 = kb + (size_t)slist[r + 3] * CD;
        a0 += (double)p0[tid] + (double)p1[tid] + (double)p2[tid] + (double)p3[tid];
        a1 += (double)p0[c1] + (double)p1[c1] + (double)p2[c1] + (double)p3[c1];
        a2 += (double)p0[c2] + (double)p1[c2] + (double)p2[c2] + (double)p3[c2];
    }
    for (; r < m; ++r) {
        const float* p0 = kb + (size_t)slist[r] * CD;
        a0 += (double)p0[tid]; a1 += (double)p0[c1]; a2 += (double)p0[c2];
    }

    float* out = Ksum + (size_t)(b * 64 + n) * CD;
    out[tid] = (float)a0; out[c1] = (float)a1; out[c2] = (float)a2;
    if (tid == 0) cnt[b * 64 + n] = m;
}

// ---------------------------------------------------------------------------
extern "C" void kernel_launch(void* const* d_in, const int* in_sizes, int n_in,
                              void* d_out, int out_size, void* d_ws, size_t ws_size,
                              hipStream_t stream)
{
    const float* query = (const float*)d_in[0];
    const float* key   = (const float*)d_in[1];
    const float* Wq    = (const float*)d_in[2];
    const float* bq    = (const float*)d_in[3];
    const float* Wk    = (const float*)d_in[4];
    const float* bk    = (const float*)d_in[5];
    const float* Wv    = (const float*)d_in[6];
    const float* bv    = (const float*)d_in[7];
    const float* Wo    = (const float*)d_in[8];
    const float* bo    = (const float*)d_in[9];

    char* ws = (char*)d_ws;
    const size_t MB = 1 << 20;
    int*    cnt   = (int*)   (ws + 0);               //   4 KB
    double* delta = (double*)(ws + 4096);            //   8 KB
    float*  uq    = (float*) (ws + 16384);           //   3 KB
    float*  bqk   = (float*) (ws + 19456);           //   3 KB
    float*  bvo   = (float*) (ws + 22528);           //   3 KB
    int*    idx   = (int*)   (ws + 32768);           // 256 KB
    float*  qT    = (float*) (ws + 1 * MB);          //   3 MB  [768][1024]
    float*  WoT   = (float*) (ws + 4 * MB);          // 2.25 MB [768][768]
    float*  Wqk   = (float*) (ws + 7 * MB);          // 2.25 MB (contiguous with Wvo)
    float*  Wvo   = Wqk + 768 * 768;                 // 2.25 MB
    float*  g     = (float*) (ws + 12 * MB);         //   3 MB  [1024][768]
    float*  Ksum  = (float*) (ws + 15 * MB);         //   3 MB
    float*  KsumT = (float*) (ws + 18 * MB);         //   3 MB  [768][1024]
    float*  P     = (float*) (ws + 21 * MB);         //  19 MB  partials

    // weight precomputes
    transpose64<<<dim3(12, 12), 256, 0, stream>>>(Wo, WoT, CD, CD);
    transpose64<<<dim3(12, 16), 256, 0, stream>>>(query, qT, ROWS, CD);
    vecmat3<<<dim3(12, 3), 256, 0, stream>>>(Wq, bk, Wk, bq, WoT, bv, uq, bqk, bvo);
    delta_q<<<ROWS / 4, 256, 0, stream>>>(query, uq, bq, bk, delta);
    // [Wqk ; Wvo] = [Wq^T@Wk ; Wv^T@Wo^T]
    gemm_w<<<dim3(12, 24, KSP), 256, 0, stream>>>(Wq, Wk, Wv, WoT, P);
    reduce_sk<<<(1536 * CD) / 256, 256, 0, stream>>>(P, nullptr, nullptr, nullptr, Wqk, 1536, 0);
    // g = query @ Wqk + bqk
    gemm_d<<<dim3(12, 16, KSP), 256, 0, stream>>>(qT, Wqk, P);
    reduce_sk<<<(ROWS * CD) / 256, 256, 0, stream>>>(P, bqk, nullptr, nullptr, g, ROWS, 1);
    // argmax assignment
    score_argmax<<<dim3(SQ / 128, BQ), 256, 0, stream>>>(g, key, delta, idx);
    // Ksum / cnt
    gather_ksum<<<dim3(NG, BQ), 256, 0, stream>>>(key, idx, Ksum, cnt);
    transpose64<<<dim3(12, 16), 256, 0, stream>>>(Ksum, KsumT, ROWS, CD);
    // out = invf*(Ksum @ Wvo) + bsc*bvo + bo
    gemm_d<<<dim3(12, 16, KSP), 256, 0, stream>>>(KsumT, Wvo, P);
    reduce_sk<<<(ROWS * CD) / 256, 256, 0, stream>>>(P, bo, bvo, cnt, (float*)d_out, ROWS, 3);
}